// Round 2
// baseline (420.559 us; speedup 1.0000x reference)
//
#include <hip/hip_runtime.h>

typedef unsigned short u16;
typedef unsigned int u32;
typedef __attribute__((ext_vector_type(4))) float f32x4;
typedef __attribute__((ext_vector_type(8))) short s16x8;

__device__ __forceinline__ u16 f2bf(float f) {
  union { float f; u32 u; } v; v.f = f;
  u32 u = v.u;
  return (u16)((u + 0x7fffu + ((u >> 16) & 1u)) >> 16);
}
__device__ __forceinline__ float bf2f(u16 b) {
  union { u32 u; float f; } v; v.u = ((u32)b) << 16;
  return v.f;
}
__device__ __forceinline__ float sigmoidf(float x) { return 1.0f / (1.0f + __expf(-x)); }

__device__ __forceinline__ void async16(const void* g, void* l) {
  __builtin_amdgcn_global_load_lds(
      (const __attribute__((address_space(1))) u32*)g,
      (__attribute__((address_space(3))) u32*)l, 16, 0, 0);
}

// ---------------------------------------------------------------------------
// merged prep: one launch for A-cast/copy + 5 conv-weight preps + fwT.
// ---------------------------------------------------------------------------
__device__ __forceinline__ void prep_w_body(
    const float* __restrict__ tw, u16* __restrict__ WcT,
    int CIN, int WK, int idx)
{
  if (idx >= 128 * WK) return;
  const int c = idx / WK;
  const int k = idx - c * WK;
  const int KR = CIN * 3;
  float v = 0.0f;
  if (k < KR) {
    const int k3 = k / CIN, cin = k - k3 * CIN;
    if (c < 64)
      v = tw[(k3 * CIN + cin) * 64 + c] + tw[(3 * CIN + k3 * CIN + cin) * 64 + c];
    else
      v = tw[(6 * CIN + k3 * CIN + cin) * 64 + (c - 64)];
  }
  WcT[idx] = f2bf(v);
}

__global__ __launch_bounds__(256) void prep_all(
    const float* __restrict__ A, u16* __restrict__ Abf, float* __restrict__ outA,
    const float* __restrict__ tb1w, u16* __restrict__ W1,
    const float* __restrict__ tb2w, u16* __restrict__ W2,
    const float* __restrict__ tb3w, u16* __restrict__ W3,
    const float* __restrict__ tb4w, u16* __restrict__ W4,
    const float* __restrict__ tb5w, u16* __restrict__ W5,
    const float* __restrict__ fw, u16* __restrict__ FWT)
{
  const int bx = blockIdx.x;
  const int tid = threadIdx.x;
  if (bx < 4096) {
    const long i = ((long)bx * 256 + tid) * 4;
    float4 v = *(const float4*)(A + i);
    *(float4*)(outA + i) = v;
    ushort4 p;
    p.x = f2bf(v.x); p.y = f2bf(v.y); p.z = f2bf(v.z); p.w = f2bf(v.w);
    *(ushort4*)(Abf + i) = p;
  } else if (bx < 4100) {
    prep_w_body(tb1w, W1, 2, 8, (bx - 4096) * 256 + tid);
  } else if (bx < 4132) {
    prep_w_body(tb2w, W2, 16, 64, (bx - 4100) * 256 + tid);
  } else if (bx < 4228) {
    prep_w_body(tb3w, W3, 64, 192, (bx - 4132) * 256 + tid);
  } else if (bx < 4260) {
    prep_w_body(tb4w, W4, 16, 64, (bx - 4228) * 256 + tid);
  } else if (bx < 4356) {
    prep_w_body(tb5w, W5, 64, 192, (bx - 4260) * 256 + tid);
  } else {
    const int idx = (bx - 4356) * 256 + tid;
    if (idx < 16 * 896) {
      const int p = idx / 896, k = idx - p * 896;
      FWT[idx] = f2bf(p < 12 ? fw[k * 12 + p] : 0.0f);
    }
  }
}

// ---------------------------------------------------------------------------
// TB1 + theta1, full MFMA. x [16][2048][24][2] fp32. W1 [128][8] bf16 prepped.
// Output U1[(b*22+t)*16+p][n] bf16, packed b64 stores.
// ---------------------------------------------------------------------------
__global__ __launch_bounds__(256) void tb1_kernel(
    const float* __restrict__ x, const u16* __restrict__ W1,
    const float* __restrict__ bias, const float* __restrict__ th1,
    u16* __restrict__ U1)
{
  __shared__ float Bts[64], Bgs[64];
  __shared__ u16 t2buf[4][16 * 64];
  const int tid = threadIdx.x;
  if (tid < 64) { Bts[tid] = bias[tid] + bias[64 + tid]; Bgs[tid] = bias[128 + tid]; }
  const int lane = tid & 63, w = tid >> 6;
  const int lm = lane & 15, q = lane >> 4;
  const int b = blockIdx.y, t = blockIdx.z;
  const int n0 = blockIdx.x * 256 + w * 64;

  s16x8 wfrag[8];
#pragma unroll
  for (int mt = 0; mt < 8; mt++) {
    wfrag[mt] = (s16x8){0, 0, 0, 0, 0, 0, 0, 0};
    if (q == 0) wfrag[mt] = *(const s16x8*)(W1 + (mt * 16 + lm) * 8);
  }
  s16x8 tfrag[2];
#pragma unroll
  for (int kk = 0; kk < 2; kk++)
#pragma unroll
    for (int j = 0; j < 8; j++)
      tfrag[kk][j] = (short)f2bf(th1[(kk * 32 + q * 8 + j) * 16 + lm]);

  float xv[4][6];
  if (q == 0) {
#pragma unroll
    for (int nt = 0; nt < 4; nt++) {
      const float* xp = x + ((long)(b * 2048 + n0 + nt * 16 + lm) * 24 + t) * 2;
#pragma unroll
      for (int j = 0; j < 6; j++) xv[nt][j] = xp[j];
    }
  }
  __syncthreads();
  float bt4[4][4], bg4[4][4];
#pragma unroll
  for (int mt = 0; mt < 4; mt++)
#pragma unroll
    for (int r = 0; r < 4; r++) {
      bt4[mt][r] = Bts[mt * 16 + q * 4 + r];
      bg4[mt][r] = Bgs[mt * 16 + q * 4 + r];
    }

  u16* myt2 = t2buf[w];
  const long orowbase = (long)((b * 22 + t) * 16) << 11;

#pragma unroll
  for (int nt = 0; nt < 4; nt++) {
    s16x8 pfrag = (s16x8){0, 0, 0, 0, 0, 0, 0, 0};
    if (q == 0) {
#pragma unroll
      for (int j = 0; j < 6; j++) pfrag[j] = (short)f2bf(xv[nt][j]);
    }
    f32x4 acc1[8];
#pragma unroll
    for (int mt = 0; mt < 8; mt++) acc1[mt] = f32x4{0.f, 0.f, 0.f, 0.f};
#pragma unroll
    for (int mt = 0; mt < 8; mt++)
      acc1[mt] = __builtin_amdgcn_mfma_f32_16x16x32_bf16(wfrag[mt], pfrag, acc1[mt], 0, 0, 0);

#pragma unroll
    for (int mt = 0; mt < 4; mt++) {
      u32 pk[2];
      u16 pv[4];
#pragma unroll
      for (int r = 0; r < 4; r++) {
        const float temp = acc1[mt][r] + bt4[mt][r];
        const float ga = acc1[mt + 4][r] + bg4[mt][r];
        pv[r] = f2bf(fmaxf(temp * sigmoidf(ga), 0.0f));
      }
      pk[0] = (u32)pv[0] | ((u32)pv[1] << 16);
      pk[1] = (u32)pv[2] | ((u32)pv[3] << 16);
      const int g = (mt * 4 + q) >> 1, half = q & 1;
      *(uint2*)(myt2 + lm * 64 + (g ^ (lm & 7)) * 8 + half * 4) = make_uint2(pk[0], pk[1]);
    }

    f32x4 acc2 = f32x4{0.f, 0.f, 0.f, 0.f};
#pragma unroll
    for (int kk = 0; kk < 2; kk++) {
      s16x8 af = *(const s16x8*)(myt2 + lm * 64 + ((kk * 4 + q) ^ (lm & 7)) * 8);
      acc2 = __builtin_amdgcn_mfma_f32_16x16x32_bf16(af, tfrag[kk], acc2, 0, 0, 0);
    }
    u16 ov[4];
#pragma unroll
    for (int r = 0; r < 4; r++) ov[r] = f2bf(acc2[r]);
    *(uint2*)(U1 + orowbase + ((long)lm << 11) + n0 + nt * 16 + q * 4) =
        make_uint2((u32)ov[0] | ((u32)ov[1] << 16), (u32)ov[2] | ((u32)ov[3] << 16));
  }
}

// ---------------------------------------------------------------------------
// Spatial GEMM (NT): C[i,col] = sum_j A[i,j] * X[col, j]  (+ optional relu)
// v2: double-buffered LDS + counted vmcnt (T3 minimum 2-phase + T4) and
// bijective XCD swizzle (T1). Steady state: 8 loads of tile k+1 in flight
// across tile k's compute; s_waitcnt vmcnt(8), never drained to 0 in-loop.
// ---------------------------------------------------------------------------
template <int RELU>
__global__ __launch_bounds__(256, 2) void sp_gemm(
    const u16* __restrict__ A, const u16* __restrict__ X,
    u16* __restrict__ C, int Ncols, int nwg)
{
  __shared__ u16 ldsA[2][128 * 64];
  __shared__ u16 ldsB[2][128 * 64];
  const int lane = threadIdx.x & 63;
  const int w = threadIdx.x >> 6;

  // bijective XCD swizzle: nwg % 8 == 0 for all call sites (704, 576).
  // hardware block h -> XCD h%8; give each XCD a contiguous chunk of work.
  const int h = blockIdx.x;
  const int bx = (h & 7) * (nwg >> 3) + (h >> 3);

  const int ct = bx >> 4;
  const int rt = bx & 15;
  const int i0 = rt * 128;
  const int c0 = ct * 128;

  const int wm = w & 1, wn = w >> 1;
  const int lm = lane & 15, q = lane >> 4;

  f32x4 acc[4][4];
#pragma unroll
  for (int a = 0; a < 4; a++)
#pragma unroll
    for (int b2 = 0; b2 < 4; b2++) acc[a][b2] = f32x4{0.f, 0.f, 0.f, 0.f};

  const int srow = lane >> 3;
  const int sg = (lane & 7) ^ srow;
  const u16* gA = A + ((long)(i0 + w * 32 + srow) << 11) + sg * 8;
  const u16* gB = X + ((long)(c0 + w * 32 + srow) << 11) + sg * 8;

  auto issue = [&](int k0, int buf) {
#pragma unroll
    for (int j = 0; j < 4; j++) {
      async16(gA + j * 16384 + k0, &ldsA[buf][w * 2048 + j * 512]);
      async16(gB + j * 16384 + k0, &ldsB[buf][w * 2048 + j * 512]);
    }
  };

  issue(0, 0);  // prologue: tile 0 in flight (8 loads/thread)

#pragma unroll 2
  for (int kt = 0; kt < 32; kt++) {
    const int buf = kt & 1;
    if (kt + 1 < 32) {
      issue((kt + 1) * 64, buf ^ 1);                     // prefetch next tile
      asm volatile("s_waitcnt vmcnt(8)" ::: "memory");   // tile kt landed
    } else {
      asm volatile("s_waitcnt vmcnt(0)" ::: "memory");   // last tile
    }
    __builtin_amdgcn_s_barrier();                        // all waves see LDS
#pragma unroll
    for (int kk = 0; kk < 2; kk++) {
      const int ph = (kk * 4 + q) ^ (lm & 7);
      s16x8 af[4], bfr[4];
#pragma unroll
      for (int mt = 0; mt < 4; mt++)
        af[mt] = *(const s16x8*)(&ldsA[buf][(wm * 64 + mt * 16 + lm) * 64 + ph * 8]);
#pragma unroll
      for (int nt = 0; nt < 4; nt++)
        bfr[nt] = *(const s16x8*)(&ldsB[buf][(wn * 64 + nt * 16 + lm) * 64 + ph * 8]);
#pragma unroll
      for (int mt = 0; mt < 4; mt++)
#pragma unroll
        for (int nt = 0; nt < 4; nt++)
          acc[mt][nt] = __builtin_amdgcn_mfma_f32_16x16x32_bf16(af[mt], bfr[nt], acc[mt][nt], 0, 0, 0);
    }
    __builtin_amdgcn_s_barrier();   // reads of buf done before it is re-staged
  }

#pragma unroll
  for (int mt = 0; mt < 4; mt++) {
#pragma unroll
    for (int r = 0; r < 4; r++) {
      const long i = i0 + wm * 64 + mt * 16 + q * 4 + r;
      u16* crow = C + i * Ncols + c0 + wn * 64 + lm;
#pragma unroll
      for (int nt = 0; nt < 4; nt++) {
        float v = acc[mt][nt][r];
        if (RELU) v = fmaxf(v, 0.0f);
        crow[nt * 16] = f2bf(v);
      }
    }
  }
}

// ---------------------------------------------------------------------------
// Streaming CIN=64 conv (WK=192): persistent-over-t blocks.
// Block = 64 nodes x 1 batch, loops t = 0..TOUT-1. 5-slot LDS ring of
// 64-row x 64-elem time segments; 1 new segment prefetched per iter
// (counted vmcnt, never drained in steady state -> 3x fewer global reads
// than one-shot blocks and 2-iteration prefetch depth).
// MODE 1 (TB3): fused theta2 epilogue, streams U2[(b*18+t)*16+p][n] per t.
//   In-loop global_store counts in vmcnt on CDNA -> steady wait vmcnt(3)
//   (retires {L,L,S} per iter), first iter vmcnt(2), last iter vmcnt(2).
// MODE 0 (TB5 tail): FC fused. h never leaves the block: per t, 2 MFMA
//   accumulate o3[n][t*64+c] @ fwT[p][k] into regs; final fp32 store of
//   out4. Eliminates the 58.7MB conv output write + 57MB fc read + launch.
// ---------------------------------------------------------------------------
template <int TIN, int MODE>
__global__ __launch_bounds__(256, 2) void conv192_stream(
    const u16* __restrict__ in, const u16* __restrict__ WcT,
    const float* __restrict__ bias, const float* __restrict__ th,
    const u16* __restrict__ fwT, const float* __restrict__ fb,
    void* __restrict__ outp)
{
  constexpr int WK = 192;
  constexpr int TOUT = TIN - 2;
  constexpr int ROWS = 16 * TIN * 64;     // input stride per node (u16)
  constexpr int RST = MODE ? 88 : 72;     // h staging stride (both 16B-mult)

  __shared__ __align__(16) u16 ring[5][64 * 64];          // 40960 B
  __shared__ __align__(16) u16 hbuf[64 * RST];            // 9216/11264 B
  __shared__ __align__(16) u16 sfw[(MODE == 0) ? 16 * 904 : 8];  // 28928 B (MODE0)

  const int tid = threadIdx.x;
  const int lane = tid & 63;
  const int w = tid >> 6;
  const int lm = lane & 15, q = lane >> 4;
  const int bx = blockIdx.x;
  const int n0 = (bx & 31) << 6;          // 32 node tiles of 64
  const int b = bx >> 5;                  // 16 batches

  // ---- conv weights -> regs (c = w*16+lm spans 64 out channels; [1]=gate) --
  s16x8 wf[2][6];
  {
    const u16* wp = WcT + (w * 16 + lm) * WK + q * 8;
#pragma unroll
    for (int kk = 0; kk < 6; kk++) {
      wf[0][kk] = *(const s16x8*)(wp + kk * 32);
      wf[1][kk] = *(const s16x8*)(wp + 64 * WK + kk * 32);
    }
  }
  const int c = w * 16 + lm;
  float bsum = bias[c] + bias[64 + c];
  float bg = bias[128 + c];

  s16x8 tfrag[2];
  if constexpr (MODE == 1) {
#pragma unroll
    for (int kk = 0; kk < 2; kk++)
#pragma unroll
      for (int j = 0; j < 8; j++)
        tfrag[kk][j] = (short)f2bf(th[(kk * 32 + q * 8 + j) * 16 + lm]);
  } else {
    // stage FC weights [16 p][896 k] -> LDS with +8 pad (904) for banks
#pragma unroll
    for (int i = 0; i < 7; i++) {
      const int g = i * 256 + tid;                 // 1792 granules of 8
      const int p = g / 112, k8 = g - p * 112;
      *(s16x8*)(sfw + p * 904 + k8 * 8) = *(const s16x8*)(fwT + g * 8);
    }
  }
  // force all prologue VGPR loads to materialize, then drain the VM queue so
  // the hand-counted vmcnt ladder below sees ONLY segment loads (+theta stores)
  asm volatile("" : "+v"(bsum), "+v"(bg));
  asm volatile("s_waitcnt vmcnt(0)" ::: "memory");

  // ---- segment staging: 64 rows x 64 elems, XOR-swizzled granules ---------
  const int srow = lane >> 3;
  const int sgl = (lane & 7) ^ srow;               // LDS[row][g] = G[row][g^row]
  long gbase[2];
#pragma unroll
  for (int i = 0; i < 2; i++)
    gbase[i] = (long)(n0 + i * 32 + w * 8 + srow) * ROWS
             + (long)b * (TIN * 64) + sgl * 8;

  auto issue_seg = [&](int ti, int slot) {
#pragma unroll
    for (int i = 0; i < 2; i++)
      async16(in + gbase[i] + ti * 64, &ring[slot][(i * 32 + w * 8) * 64]);
  };

  // prologue: segs 0..3 in flight (8 loads/thread)
  issue_seg(0, 0); issue_seg(1, 1); issue_seg(2, 2); issue_seg(3, 3);

  f32x4 accfc = f32x4{0.f, 0.f, 0.f, 0.f};
  // ring slots for segs t, t+1, t+2, t+3(in flight), t+4(prefetch target)
  int sa = 0, sb = 1, sc = 2, sd = 3, sp = 4;

  auto body = [&](int t, bool do_issue) {
    if (do_issue) issue_seg(t + 4, sp);            // sp held seg t-1: free now
    f32x4 acc[4][2];
#pragma unroll
    for (int m = 0; m < 4; m++) {
      acc[m][0] = f32x4{0.f, 0.f, 0.f, 0.f};
      acc[m][1] = f32x4{0.f, 0.f, 0.f, 0.f};
    }
#pragma unroll
    for (int kk = 0; kk < 6; kk++) {
      const int s = kk >> 1;
      const u16* segp = ring[s == 0 ? sa : (s == 1 ? sb : sc)];
      const int ph = (((kk & 1) * 4 + q) ^ (lm & 7));
#pragma unroll
      for (int mt = 0; mt < 4; mt++) {
        s16x8 pf = *(const s16x8*)(segp + (mt * 16 + lm) * 64 + ph * 8);
        acc[mt][0] = __builtin_amdgcn_mfma_f32_16x16x32_bf16(pf, wf[0][kk], acc[mt][0], 0, 0, 0);
        acc[mt][1] = __builtin_amdgcn_mfma_f32_16x16x32_bf16(pf, wf[1][kk], acc[mt][1], 0, 0, 0);
      }
    }
    // gate epilogue -> hbuf
#pragma unroll
    for (int mt = 0; mt < 4; mt++)
#pragma unroll
      for (int r = 0; r < 4; r++) {
        const int pos = mt * 16 + q * 4 + r;
        const float temp = acc[mt][0][r] + bsum;
        const float ga = acc[mt][1][r] + bg;
        hbuf[pos * RST + c] = f2bf(fmaxf(temp * sigmoidf(ga), 0.0f));
      }
    asm volatile("s_waitcnt lgkmcnt(0)" ::: "memory");
    __builtin_amdgcn_s_barrier();
    if constexpr (MODE == 0) {
#pragma unroll
      for (int kk = 0; kk < 2; kk++) {
        s16x8 af = *(const s16x8*)(hbuf + (w * 16 + lm) * RST + kk * 32 + q * 8);
        s16x8 bfr = *(const s16x8*)(sfw + lm * 904 + t * 64 + kk * 32 + q * 8);
        accfc = __builtin_amdgcn_mfma_f32_16x16x32_bf16(af, bfr, accfc, 0, 0, 0);
      }
    } else {
      const long orowbase = (long)((b * TOUT + t) * 16) << 11;
      f32x4 a2 = f32x4{0.f, 0.f, 0.f, 0.f};
#pragma unroll
      for (int kk = 0; kk < 2; kk++) {
        s16x8 af = *(const s16x8*)(hbuf + (w * 16 + lm) * RST + kk * 32 + q * 8);
        a2 = __builtin_amdgcn_mfma_f32_16x16x32_bf16(af, tfrag[kk], a2, 0, 0, 0);
      }
      u16 ov[4];
#pragma unroll
      for (int r = 0; r < 4; r++) ov[r] = f2bf(a2[r]);
      *(uint2*)((u16*)outp + orowbase + ((long)lm << 11) + n0 + w * 16 + q * 4) =
          make_uint2((u32)ov[0] | ((u32)ov[1] << 16), (u32)ov[2] | ((u32)ov[3] << 16));
    }
    const int t0 = sa; sa = sb; sb = sc; sc = sd; sd = sp; sp = t0;
  };

  // iter 0: queue = 8 prologue loads; vmcnt(2) -> segs 0,1,2 landed
  asm volatile("s_waitcnt vmcnt(2) lgkmcnt(0)" ::: "memory");
  __builtin_amdgcn_s_barrier();
  body(0, true);
#pragma unroll 1
  for (int t = 1; t < TOUT - 1; ++t) {
    if constexpr (MODE == 1)
      asm volatile("s_waitcnt vmcnt(3) lgkmcnt(0)" ::: "memory");  // retire L,L,S
    else
      asm volatile("s_waitcnt vmcnt(2) lgkmcnt(0)" ::: "memory");  // retire L,L
    __builtin_amdgcn_s_barrier();
    body(t, t + 4 < TIN);
  }
  if constexpr (MODE == 1)
    asm volatile("s_waitcnt vmcnt(2) lgkmcnt(0)" ::: "memory");    // 2 stores left
  else
    asm volatile("s_waitcnt vmcnt(0) lgkmcnt(0)" ::: "memory");
  __builtin_amdgcn_s_barrier();
  body(TOUT - 1, false);

  if constexpr (MODE == 0) {
    if (lm < 12) {
      float* outF = (float*)outp;
      const float bfc = fb[lm];
#pragma unroll
      for (int r = 0; r < 4; r++) {
        const int n = n0 + w * 16 + q * 4 + r;
        outF[((long)b * 2048 + n) * 12 + lm] = accfc[r] + bfc;
      }
    }
  }
}

// ---------------------------------------------------------------------------
// CIN=16 conv (WK=64), R6-style single-bt block (best measured for CIN=16):
// stage 128 rows once, sync, 2 kk x 16 MFMA, epilogue via LDS(72).
// Output [n][16][TOUT][64].
// ---------------------------------------------------------------------------
template <int TIN>
__global__ __launch_bounds__(256, 3) void conv64_k(
    const u16* __restrict__ in, const u16* __restrict__ WcT,
    const float* __restrict__ bias, u16* __restrict__ out)
{
  constexpr int TOUT = TIN - 2;
  constexpr int ROWS = 16 * TIN * 16;
  __shared__ u16 lds[128 * 72];

  const int tid = threadIdx.x;
  const int lane = tid & 63;
  const int w = tid >> 6;
  const int lm = lane & 15, q = lane >> 4;
  const int pos0 = blockIdx.x << 7;
  const int n0 = pos0 & 2047;
  const int bt = pos0 >> 11;
  const int b = bt / TOUT, t = bt - b * TOUT;
  const long cbase = (long)n0 * ROWS + (b * TIN + t) * 16;

  const int srow_off = lane >> 3;
  const int sgl = (lane & 7) ^ srow_off;
#pragma unroll
  for (int i = 0; i < 4; i++) {
    const int row = i * 32 + w * 8 + srow_off;
    async16(in + cbase + (long)row * ROWS + sgl * 8,
            lds + (i * 32 + w * 8) * 64);
  }

  s16x8 wf[2][2];
  {
    const u16* wp = WcT + (w * 16 + lm) * 64 + q * 8;
#pragma unroll
    for (int kk = 0; kk < 2; kk++) {
      wf[0][kk] = *(const s16x8*)(wp + kk * 32);
      wf[1][kk] = *(const s16x8*)(wp + 64 * 64 + kk * 32);
    }
  }
  const int c = w * 16 + lm;
  const float bsum = bias[c] + bias[64 + c];
  const float bg = bias[128 + c];

  f32x4 acc[8][2];
#pragma unroll
  for (int m = 0; m < 8; m++) {
    acc[m][0] = f32x4{0.f, 0.f, 0.f, 0.f};
    acc[m][1] = f32x4{0.f, 0.f, 0.f, 0.f};
  }

  __syncthreads();

#pragma unroll
  for (int kk = 0; kk < 2; kk++) {
    const int ph = ((kk * 4 + q) ^ (lm & 7));
#pragma unroll
    for (int mt = 0; mt < 8; mt++) {
      s16x8 pf = *(const s16x8*)(lds + (mt * 16 + lm) * 64 + ph * 8);
      acc[mt][0] = __builtin_amdgcn_mfma_f32_16x16x32_bf16(pf, wf[0][kk], acc[mt][0], 0, 0, 0);
      acc[mt][1] = __builtin_amdgcn_mfma_f32_16x16x32_bf16(pf, wf[1][kk], acc[mt][1], 0, 0, 0);
    }
  }

  __syncthreads();                    // all patch reads done; reuse LDS

#pragma unroll
  for (int mt = 0; mt < 8; mt++) {
#pragma unroll
    for (int r = 0; r < 4; r++) {
      const int pos = mt * 16 + q * 4 + r;
      const float temp = acc[mt][0][r] + bsum;
      const float ga = acc[mt][1][r] + bg;
      lds[pos * 72 + c] = f2bf(fmaxf(temp * sigmoidf(ga), 0.0f));
    }
  }
  __syncthreads();

  const int pos2 = tid >> 1, half = tid & 1;
  u16* orow = out + ((((long)(n0 + pos2) * 16 + b) * TOUT + t) << 6) + half * 32;
#pragma unroll
  for (int i = 0; i < 4; i++)
    *(uint4*)(orow + i * 8) = *(const uint4*)(lds + pos2 * 72 + half * 32 + i * 8);
}

// ---------------------------------------------------------------------------
extern "C" void kernel_launch(void* const* d_in, const int* in_sizes, int n_in,
                              void* d_out, int out_size, void* d_ws, size_t ws_size,
                              hipStream_t stream)
{
  const float* x    = (const float*)d_in[0];
  const float* A    = (const float*)d_in[1];
  const float* tb1w = (const float*)d_in[2];
  const float* tb1b = (const float*)d_in[3];
  const float* th1  = (const float*)d_in[4];
  const float* tb2w = (const float*)d_in[5];
  const float* tb2b = (const float*)d_in[6];
  const float* tb3w = (const float*)d_in[7];
  const float* tb3b = (const float*)d_in[8];
  const float* th2  = (const float*)d_in[9];
  const float* tb4w = (const float*)d_in[10];
  const float* tb4b = (const float*)d_in[11];
  const float* tb5w = (const float*)d_in[12];
  const float* tb5b = (const float*)d_in[13];
  const float* fw   = (const float*)d_in[14];
  const float* fb   = (const float*)d_in[15];
  float* out = (float*)d_out;

  char* ws = (char*)d_ws;
  u16* Abf  = (u16*)(ws + 0);            //  8,388,608 B
  u16* W2   = (u16*)(ws + 8388608);      //     16,384
  u16* W3   = (u16*)(ws + 8404992);      //     49,152
  u16* W4   = (u16*)(ws + 8454144);      //     16,384
  u16* W5   = (u16*)(ws + 8470528);      //     49,152
  u16* bufA = (u16*)(ws + 8519680);      // 92,274,688 (max live use 83.9 MB)
  u16* bufB = (u16*)(ws + 100794368);    // 92,274,688
  u16* W1   = (u16*)(ws + 8519680 + 88000000);  // 2 KB, in bufA tail slack
  u16* FWT  = (u16*)(ws + 8519680 + 88004096);  // 28,672 B, bufA tail slack

  prep_all<<<4412, 256, 0, stream>>>(A, Abf, out + 393216,
                                     tb1w, W1, tb2w, W2, tb3w, W3,
                                     tb4w, W4, tb5w, W5, fw, FWT);

  // ---- block 1:  U1 = TB1(x)*th1; t2 = relu(A*U1); out1 = TB2(t2)
  tb1_kernel<<<dim3(8, 16, 22), 256, 0, stream>>>(x, W1, tb1b, th1, bufA);
  sp_gemm<1><<<44 * 16, 256, 0, stream>>>(Abf, bufA, bufB, 5632, 44 * 16);
  conv64_k<22><<<5120, 256, 0, stream>>>(bufB, W2, tb2b, bufA);              // -> [n][16][20][64]
  // ---- block 2:  U2 = TB3(out1)*th2 (fused, streaming); t2 = relu(A*U2); TB4(t2)
  conv192_stream<20, 1><<<512, 256, 0, stream>>>(bufA, W3, tb3b, th2,
                                                 nullptr, nullptr, bufB);    // -> U2 [(b,t,p)][n]
  sp_gemm<1><<<36 * 16, 256, 0, stream>>>(Abf, bufB, bufA, 4608, 36 * 16);
  conv64_k<18><<<4096, 256, 0, stream>>>(bufA, W4, tb4b, bufB);              // -> [n][16][16][64]
  // ---- tail: TB5 + FC fused, streaming
  conv192_stream<16, 0><<<512, 256, 0, stream>>>(bufB, W5, tb5b, nullptr,
                                                 FWT, fb, out);              // -> out4 fp32
}

// Round 3
// 368.254 us; speedup vs baseline: 1.1420x; 1.1420x over previous
//
#include <hip/hip_runtime.h>

typedef unsigned short u16;
typedef unsigned int u32;
typedef __attribute__((ext_vector_type(4))) float f32x4;
typedef __attribute__((ext_vector_type(8))) short s16x8;

__device__ __forceinline__ u16 f2bf(float f) {
  union { float f; u32 u; } v; v.f = f;
  u32 u = v.u;
  return (u16)((u + 0x7fffu + ((u >> 16) & 1u)) >> 16);
}
__device__ __forceinline__ float bf2f(u16 b) {
  union { u32 u; float f; } v; v.u = ((u32)b) << 16;
  return v.f;
}
__device__ __forceinline__ float sigmoidf(float x) { return 1.0f / (1.0f + __expf(-x)); }

__device__ __forceinline__ void async16(const void* g, void* l) {
  __builtin_amdgcn_global_load_lds(
      (const __attribute__((address_space(1))) u32*)g,
      (__attribute__((address_space(3))) u32*)l, 16, 0, 0);
}

// ---------------------------------------------------------------------------
// merged prep: one launch for A-cast/copy + 5 conv-weight preps + fwT.
// ---------------------------------------------------------------------------
__device__ __forceinline__ void prep_w_body(
    const float* __restrict__ tw, u16* __restrict__ WcT,
    int CIN, int WK, int idx)
{
  if (idx >= 128 * WK) return;
  const int c = idx / WK;
  const int k = idx - c * WK;
  const int KR = CIN * 3;
  float v = 0.0f;
  if (k < KR) {
    const int k3 = k / CIN, cin = k - k3 * CIN;
    if (c < 64)
      v = tw[(k3 * CIN + cin) * 64 + c] + tw[(3 * CIN + k3 * CIN + cin) * 64 + c];
    else
      v = tw[(6 * CIN + k3 * CIN + cin) * 64 + (c - 64)];
  }
  WcT[idx] = f2bf(v);
}

__global__ __launch_bounds__(256) void prep_all(
    const float* __restrict__ A, u16* __restrict__ Abf, float* __restrict__ outA,
    const float* __restrict__ tb1w, u16* __restrict__ W1,
    const float* __restrict__ tb2w, u16* __restrict__ W2,
    const float* __restrict__ tb3w, u16* __restrict__ W3,
    const float* __restrict__ tb4w, u16* __restrict__ W4,
    const float* __restrict__ tb5w, u16* __restrict__ W5,
    const float* __restrict__ fw, u16* __restrict__ FWT)
{
  const int bx = blockIdx.x;
  const int tid = threadIdx.x;
  if (bx < 4096) {
    const long i = ((long)bx * 256 + tid) * 4;
    float4 v = *(const float4*)(A + i);
    *(float4*)(outA + i) = v;
    ushort4 p;
    p.x = f2bf(v.x); p.y = f2bf(v.y); p.z = f2bf(v.z); p.w = f2bf(v.w);
    *(ushort4*)(Abf + i) = p;
  } else if (bx < 4100) {
    prep_w_body(tb1w, W1, 2, 8, (bx - 4096) * 256 + tid);
  } else if (bx < 4132) {
    prep_w_body(tb2w, W2, 16, 64, (bx - 4100) * 256 + tid);
  } else if (bx < 4228) {
    prep_w_body(tb3w, W3, 64, 192, (bx - 4132) * 256 + tid);
  } else if (bx < 4260) {
    prep_w_body(tb4w, W4, 16, 64, (bx - 4228) * 256 + tid);
  } else if (bx < 4356) {
    prep_w_body(tb5w, W5, 64, 192, (bx - 4260) * 256 + tid);
  } else {
    const int idx = (bx - 4356) * 256 + tid;
    if (idx < 16 * 896) {
      const int p = idx / 896, k = idx - p * 896;
      FWT[idx] = f2bf(p < 12 ? fw[k * 12 + p] : 0.0f);
    }
  }
}

// ---------------------------------------------------------------------------
// TB1 + theta1, full MFMA. x [16][2048][24][2] fp32. W1 [128][8] bf16 prepped.
// Output U1[(b*22+t)*16+p][n] bf16, packed b64 stores.
// ---------------------------------------------------------------------------
__global__ __launch_bounds__(256) void tb1_kernel(
    const float* __restrict__ x, const u16* __restrict__ W1,
    const float* __restrict__ bias, const float* __restrict__ th1,
    u16* __restrict__ U1)
{
  __shared__ float Bts[64], Bgs[64];
  __shared__ u16 t2buf[4][16 * 64];
  const int tid = threadIdx.x;
  if (tid < 64) { Bts[tid] = bias[tid] + bias[64 + tid]; Bgs[tid] = bias[128 + tid]; }
  const int lane = tid & 63, w = tid >> 6;
  const int lm = lane & 15, q = lane >> 4;
  const int b = blockIdx.y, t = blockIdx.z;
  const int n0 = blockIdx.x * 256 + w * 64;

  s16x8 wfrag[8];
#pragma unroll
  for (int mt = 0; mt < 8; mt++) {
    wfrag[mt] = (s16x8){0, 0, 0, 0, 0, 0, 0, 0};
    if (q == 0) wfrag[mt] = *(const s16x8*)(W1 + (mt * 16 + lm) * 8);
  }
  s16x8 tfrag[2];
#pragma unroll
  for (int kk = 0; kk < 2; kk++)
#pragma unroll
    for (int j = 0; j < 8; j++)
      tfrag[kk][j] = (short)f2bf(th1[(kk * 32 + q * 8 + j) * 16 + lm]);

  float xv[4][6];
  if (q == 0) {
#pragma unroll
    for (int nt = 0; nt < 4; nt++) {
      const float* xp = x + ((long)(b * 2048 + n0 + nt * 16 + lm) * 24 + t) * 2;
#pragma unroll
      for (int j = 0; j < 6; j++) xv[nt][j] = xp[j];
    }
  }
  __syncthreads();
  float bt4[4][4], bg4[4][4];
#pragma unroll
  for (int mt = 0; mt < 4; mt++)
#pragma unroll
    for (int r = 0; r < 4; r++) {
      bt4[mt][r] = Bts[mt * 16 + q * 4 + r];
      bg4[mt][r] = Bgs[mt * 16 + q * 4 + r];
    }

  u16* myt2 = t2buf[w];
  const long orowbase = (long)((b * 22 + t) * 16) << 11;

#pragma unroll
  for (int nt = 0; nt < 4; nt++) {
    s16x8 pfrag = (s16x8){0, 0, 0, 0, 0, 0, 0, 0};
    if (q == 0) {
#pragma unroll
      for (int j = 0; j < 6; j++) pfrag[j] = (short)f2bf(xv[nt][j]);
    }
    f32x4 acc1[8];
#pragma unroll
    for (int mt = 0; mt < 8; mt++) acc1[mt] = f32x4{0.f, 0.f, 0.f, 0.f};
#pragma unroll
    for (int mt = 0; mt < 8; mt++)
      acc1[mt] = __builtin_amdgcn_mfma_f32_16x16x32_bf16(wfrag[mt], pfrag, acc1[mt], 0, 0, 0);

#pragma unroll
    for (int mt = 0; mt < 4; mt++) {
      u32 pk[2];
      u16 pv[4];
#pragma unroll
      for (int r = 0; r < 4; r++) {
        const float temp = acc1[mt][r] + bt4[mt][r];
        const float ga = acc1[mt + 4][r] + bg4[mt][r];
        pv[r] = f2bf(fmaxf(temp * sigmoidf(ga), 0.0f));
      }
      pk[0] = (u32)pv[0] | ((u32)pv[1] << 16);
      pk[1] = (u32)pv[2] | ((u32)pv[3] << 16);
      const int g = (mt * 4 + q) >> 1, half = q & 1;
      *(uint2*)(myt2 + lm * 64 + (g ^ (lm & 7)) * 8 + half * 4) = make_uint2(pk[0], pk[1]);
    }

    f32x4 acc2 = f32x4{0.f, 0.f, 0.f, 0.f};
#pragma unroll
    for (int kk = 0; kk < 2; kk++) {
      s16x8 af = *(const s16x8*)(myt2 + lm * 64 + ((kk * 4 + q) ^ (lm & 7)) * 8);
      acc2 = __builtin_amdgcn_mfma_f32_16x16x32_bf16(af, tfrag[kk], acc2, 0, 0, 0);
    }
    u16 ov[4];
#pragma unroll
    for (int r = 0; r < 4; r++) ov[r] = f2bf(acc2[r]);
    *(uint2*)(U1 + orowbase + ((long)lm << 11) + n0 + nt * 16 + q * 4) =
        make_uint2((u32)ov[0] | ((u32)ov[1] << 16), (u32)ov[2] | ((u32)ov[3] << 16));
  }
}

// ---------------------------------------------------------------------------
// Spatial GEMM (NT): C[i,col] = sum_j A[i,j] * X[col, j]  (+ optional relu)
// R1 version (measured 54 us, ~874 TF = m97-structure ceiling). Do not
// re-pipeline: R2's dbuf+vmcnt variant cost occupancy and regressed.
// ---------------------------------------------------------------------------
template <int RELU>
__global__ __launch_bounds__(256, 3) void sp_gemm(
    const u16* __restrict__ A, const u16* __restrict__ X,
    u16* __restrict__ C, int Ncols)
{
  __shared__ u16 ldsA[128 * 64];
  __shared__ u16 ldsB[128 * 64];
  const int lane = threadIdx.x & 63;
  const int w = threadIdx.x >> 6;

  const int ct = blockIdx.x >> 4;
  const int rt = blockIdx.x & 15;
  const int i0 = rt * 128;
  const int c0 = ct * 128;

  const int wm = w & 1, wn = w >> 1;
  const int lm = lane & 15, q = lane >> 4;

  f32x4 acc[4][4];
#pragma unroll
  for (int a = 0; a < 4; a++)
#pragma unroll
    for (int b2 = 0; b2 < 4; b2++) acc[a][b2] = f32x4{0.f, 0.f, 0.f, 0.f};

  const int srow = lane >> 3;
  const int sg = (lane & 7) ^ srow;
  const u16* gA = A + ((long)(i0 + w * 32 + srow) << 11) + sg * 8;
  const u16* gB = X + ((long)(c0 + w * 32 + srow) << 11) + sg * 8;
  u16* lA = ldsA + w * 2048;
  u16* lB = ldsB + w * 2048;

  for (int k0 = 0; k0 < 2048; k0 += 64) {
    __syncthreads();
#pragma unroll
    for (int j = 0; j < 4; j++) {
      async16(gA + j * 16384 + k0, lA + j * 512);
      async16(gB + j * 16384 + k0, lB + j * 512);
    }
    __syncthreads();
#pragma unroll
    for (int kk = 0; kk < 2; kk++) {
      const int ph = (kk * 4 + q) ^ (lm & 7);
      s16x8 af[4], bfr[4];
#pragma unroll
      for (int mt = 0; mt < 4; mt++)
        af[mt] = *(const s16x8*)(ldsA + (wm * 64 + mt * 16 + lm) * 64 + ph * 8);
#pragma unroll
      for (int nt = 0; nt < 4; nt++)
        bfr[nt] = *(const s16x8*)(ldsB + (wn * 64 + nt * 16 + lm) * 64 + ph * 8);
#pragma unroll
      for (int mt = 0; mt < 4; mt++)
#pragma unroll
        for (int nt = 0; nt < 4; nt++)
          acc[mt][nt] = __builtin_amdgcn_mfma_f32_16x16x32_bf16(af[mt], bfr[nt], acc[mt][nt], 0, 0, 0);
    }
  }

#pragma unroll
  for (int mt = 0; mt < 4; mt++) {
#pragma unroll
    for (int r = 0; r < 4; r++) {
      const long i = i0 + wm * 64 + mt * 16 + q * 4 + r;
      u16* crow = C + i * Ncols + c0 + wn * 64 + lm;
#pragma unroll
      for (int nt = 0; nt < 4; nt++) {
        float v = acc[mt][nt][r];
        if (RELU) v = fmaxf(v, 0.0f);
        crow[nt * 16] = f2bf(v);
      }
    }
  }
}

// ---------------------------------------------------------------------------
// Fused timeblock pair, streaming over t. Block = 64 nodes x 1 batch.
// Input: sp_gemm output [2048 nodes][NC = TIN*256], col = (b*TIN+t)*16+p.
// Per iter t (0..TIN-3):
//   gate(vmcnt,lgkm) + barrier; maybe issue one 2-seg prefetch pair;
//   TB-first (K=64, W1c) over ring segs t..t+3 -> gate -> h ring slot;
//   lgkm+barrier; t>=2: TB-second (K=192, W2c) over h(t-2..t) -> gate -> h3;
//   lgkm+barrier; MODE1: theta MFMA + store U2 row; MODE0: FC MFMA accumulate.
// Ring: 8 slots x [64 rows][16 u16] (1 t-step each); pairs staged with all
// 256 threads (1 load/thread); counted vmcnt (stores count too in MODE1).
// Seg t+3 of each window hits zero weights (k>=48) -> stale slot data is
// harmless (finite bf16 x 0).
// ---------------------------------------------------------------------------
template <int TIN, int MODE>
__global__ __launch_bounds__(256, 2) void tbf_fused(
    const u16* __restrict__ in, const u16* __restrict__ W1c,
    const float* __restrict__ b1, const u16* __restrict__ W2c,
    const float* __restrict__ b2, const float* __restrict__ th,
    const u16* __restrict__ fwT, const float* __restrict__ fb,
    u16* __restrict__ outU, float* __restrict__ outF)
{
  constexpr int T1OUT = TIN - 2;            // TB-first outputs (iters)
  constexpr int T2OUT = TIN - 4;            // TB-second outputs
  constexpr int NC = TIN * 256;             // input row stride (u16)

  __shared__ __align__(16) u16 ring[8 * 1024];       // 16384 B
  __shared__ __align__(16) u16 h2r[3 * 64 * 72];     // 27648 B
  __shared__ __align__(16) u16 h3b[64 * 72];         //  9216 B
  __shared__ __align__(16) u16 sfw[(MODE == 0) ? 12 * 904 : 8];  // 21696 B (MODE0)

  const int tid = threadIdx.x;
  const int lane = tid & 63;
  const int w = tid >> 6;
  const int lm = lane & 15, q = lane >> 4;
  const int bx = blockIdx.x;
  const int n0 = (bx & 31) << 6;
  const int b = bx >> 5;

  // ---- weights -> regs ----------------------------------------------------
  s16x8 wfA[2][2];
  {
    const u16* wp = W1c + (w * 16 + lm) * 64 + q * 8;
#pragma unroll
    for (int kk = 0; kk < 2; kk++) {
      wfA[0][kk] = *(const s16x8*)(wp + kk * 32);
      wfA[1][kk] = *(const s16x8*)(wp + 64 * 64 + kk * 32);
    }
  }
  s16x8 wfB[2][6];
  {
    const u16* wp = W2c + (w * 16 + lm) * 192 + q * 8;
#pragma unroll
    for (int kk = 0; kk < 6; kk++) {
      wfB[0][kk] = *(const s16x8*)(wp + kk * 32);
      wfB[1][kk] = *(const s16x8*)(wp + 64 * 192 + kk * 32);
    }
  }
  const int c = w * 16 + lm;
  float bsA = b1[c] + b1[64 + c];
  float bgA = b1[128 + c];
  float bsB = b2[c] + b2[64 + c];
  float bgB = b2[128 + c];

  s16x8 tfrag[2];
  const int srow12 = (lm < 12) ? lm : (lm - 12);
  if constexpr (MODE == 1) {
#pragma unroll
    for (int kk = 0; kk < 2; kk++)
#pragma unroll
      for (int j = 0; j < 8; j++)
        tfrag[kk][j] = (short)f2bf(th[(kk * 32 + q * 8 + j) * 16 + lm]);
  } else {
    // FC weights: 12 real p-rows, stride 904 (16B mult, bank-spread).
#pragma unroll
    for (int i = 0; i < 6; i++) {
      const int g = i * 256 + tid;              // granules of 8 u16
      if (g < 12 * 112) {
        const int p = g / 112, k8 = g - p * 112;
        *(s16x8*)(sfw + p * 904 + k8 * 8) = *(const s16x8*)(fwT + g * 8);
      }
    }
  }
  // materialize prologue VGPR loads, then drain VM queue so the counted
  // vmcnt ladder below sees only segment loads (+ MODE1 theta stores).
  asm volatile("" : "+v"(bsA), "+v"(bgA), "+v"(bsB), "+v"(bgB));
  asm volatile("s_waitcnt vmcnt(0)" ::: "memory");

  // ---- segment staging: pairs of 2 t-steps, all 256 threads, 1 load each --
  const int k7 = tid & 127;                   // position within a seg (x16B)
  const int segsel = tid >> 7;                // 0/1: which seg of the pair
  const u16* rowp = in + (long)(n0 + (k7 >> 1)) * NC + (long)(b * TIN) * 16 + (k7 & 1) * 8;

  auto issue_pair = [&](int tp) {
    const int seg = tp + segsel;
    async16(rowp + seg * 16, ring + ((seg & 7) << 10) + k7 * 8);
  };

  issue_pair(0); issue_pair(2); issue_pair(4);   // segs 0..5 in flight

  u16* h2w = h2r;                 // h(t)   write slot
  u16* h2m = h2r + 64 * 72;       // h(t-1)
  u16* h2o = h2r + 2 * 64 * 72;   // h(t-2)
  f32x4 accfc = f32x4{0.f, 0.f, 0.f, 0.f};

#pragma unroll 1
  for (int t = 0; t < T1OUT; ++t) {
    // gate: required pair retired. MODE1 queue per iter = {L, S}; MODE0 = {L}.
    if constexpr (MODE == 1) {
      if (t < 3) asm volatile("s_waitcnt vmcnt(1) lgkmcnt(0)" ::: "memory");
      else       asm volatile("s_waitcnt vmcnt(2) lgkmcnt(0)" ::: "memory");
    } else {
      if (t < 13) asm volatile("s_waitcnt vmcnt(1) lgkmcnt(0)" ::: "memory");
      else        asm volatile("s_waitcnt vmcnt(0) lgkmcnt(0)" ::: "memory");
    }
    __builtin_amdgcn_s_barrier();

    if (((t & 1) == 0) && t <= TIN - 8) issue_pair(t + 6);

    // ---- TB-first: K=64 window over ring segs t..t+3 ----
    f32x4 aA[4][2];
#pragma unroll
    for (int m = 0; m < 4; m++) {
      aA[m][0] = f32x4{0.f, 0.f, 0.f, 0.f};
      aA[m][1] = f32x4{0.f, 0.f, 0.f, 0.f};
    }
#pragma unroll
    for (int kk = 0; kk < 2; kk++) {
      const int slotb = ((t + 2 * kk + (q >> 1)) & 7) << 10;
      const int off = slotb + (q & 1) * 8;
#pragma unroll
      for (int mt = 0; mt < 4; mt++) {
        s16x8 pf = *(const s16x8*)(ring + off + (mt * 16 + lm) * 16);
        aA[mt][0] = __builtin_amdgcn_mfma_f32_16x16x32_bf16(pf, wfA[0][kk], aA[mt][0], 0, 0, 0);
        aA[mt][1] = __builtin_amdgcn_mfma_f32_16x16x32_bf16(pf, wfA[1][kk], aA[mt][1], 0, 0, 0);
      }
    }
    // gate epilogue -> h2w
#pragma unroll
    for (int mt = 0; mt < 4; mt++)
#pragma unroll
      for (int r = 0; r < 4; r++) {
        const int pos = mt * 16 + q * 4 + r;
        const float temp = aA[mt][0][r] + bsA;
        const float ga = aA[mt][1][r] + bgA;
        h2w[pos * 72 + c] = f2bf(fmaxf(temp * sigmoidf(ga), 0.0f));
      }
    asm volatile("s_waitcnt lgkmcnt(0)" ::: "memory");
    __builtin_amdgcn_s_barrier();

    if (t >= 2) {
      // ---- TB-second: K=192 over h(t-2), h(t-1), h(t) ----
      f32x4 aB[4][2];
#pragma unroll
      for (int m = 0; m < 4; m++) {
        aB[m][0] = f32x4{0.f, 0.f, 0.f, 0.f};
        aB[m][1] = f32x4{0.f, 0.f, 0.f, 0.f};
      }
#pragma unroll
      for (int kk3 = 0; kk3 < 6; kk3++) {
        const u16* hp = (kk3 < 2) ? h2o : ((kk3 < 4) ? h2m : h2w);
        const int gr = (kk3 & 1) * 4 + q;
#pragma unroll
        for (int mt = 0; mt < 4; mt++) {
          s16x8 af = *(const s16x8*)(hp + (mt * 16 + lm) * 72 + gr * 8);
          aB[mt][0] = __builtin_amdgcn_mfma_f32_16x16x32_bf16(af, wfB[0][kk3], aB[mt][0], 0, 0, 0);
          aB[mt][1] = __builtin_amdgcn_mfma_f32_16x16x32_bf16(af, wfB[1][kk3], aB[mt][1], 0, 0, 0);
        }
      }
      // gate epilogue -> h3b
#pragma unroll
      for (int mt = 0; mt < 4; mt++)
#pragma unroll
        for (int r = 0; r < 4; r++) {
          const int pos = mt * 16 + q * 4 + r;
          const float temp = aB[mt][0][r] + bsB;
          const float ga = aB[mt][1][r] + bgB;
          h3b[pos * 72 + c] = f2bf(fmaxf(temp * sigmoidf(ga), 0.0f));
        }
      asm volatile("s_waitcnt lgkmcnt(0)" ::: "memory");
      __builtin_amdgcn_s_barrier();

      const int t2 = t - 2;
      if constexpr (MODE == 1) {
        f32x4 a4 = f32x4{0.f, 0.f, 0.f, 0.f};
#pragma unroll
        for (int kk = 0; kk < 2; kk++) {
          s16x8 af = *(const s16x8*)(h3b + (w * 16 + lm) * 72 + kk * 32 + q * 8);
          a4 = __builtin_amdgcn_mfma_f32_16x16x32_bf16(af, tfrag[kk], a4, 0, 0, 0);
        }
        u16 ov[4];
#pragma unroll
        for (int r = 0; r < 4; r++) ov[r] = f2bf(a4[r]);
        const long orowbase = (long)((b * T2OUT + t2) * 16) << 11;
        *(uint2*)(outU + orowbase + ((long)lm << 11) + n0 + w * 16 + q * 4) =
            make_uint2((u32)ov[0] | ((u32)ov[1] << 16), (u32)ov[2] | ((u32)ov[3] << 16));
      } else {
#pragma unroll
        for (int kk = 0; kk < 2; kk++) {
          s16x8 af = *(const s16x8*)(h3b + (w * 16 + lm) * 72 + kk * 32 + q * 8);
          s16x8 bfr = *(const s16x8*)(sfw + srow12 * 904 + t2 * 64 + kk * 32 + q * 8);
          accfc = __builtin_amdgcn_mfma_f32_16x16x32_bf16(af, bfr, accfc, 0, 0, 0);
        }
      }
    }
    // rotate h slots: (t-2) slot becomes next write slot
    u16* tmp = h2o; h2o = h2m; h2m = h2w; h2w = tmp;
  }

  if constexpr (MODE == 0) {
    if (lm < 12) {
      const float bfc = fb[lm];
#pragma unroll
      for (int r = 0; r < 4; r++) {
        const int n = n0 + w * 16 + q * 4 + r;
        outF[((long)b * 2048 + n) * 12 + lm] = accfc[r] + bfc;
      }
    }
  }
}

// ---------------------------------------------------------------------------
extern "C" void kernel_launch(void* const* d_in, const int* in_sizes, int n_in,
                              void* d_out, int out_size, void* d_ws, size_t ws_size,
                              hipStream_t stream)
{
  const float* x    = (const float*)d_in[0];
  const float* A    = (const float*)d_in[1];
  const float* tb1w = (const float*)d_in[2];
  const float* tb1b = (const float*)d_in[3];
  const float* th1  = (const float*)d_in[4];
  const float* tb2w = (const float*)d_in[5];
  const float* tb2b = (const float*)d_in[6];
  const float* tb3w = (const float*)d_in[7];
  const float* tb3b = (const float*)d_in[8];
  const float* th2  = (const float*)d_in[9];
  const float* tb4w = (const float*)d_in[10];
  const float* tb4b = (const float*)d_in[11];
  const float* tb5w = (const float*)d_in[12];
  const float* tb5b = (const float*)d_in[13];
  const float* fw   = (const float*)d_in[14];
  const float* fb   = (const float*)d_in[15];
  float* out = (float*)d_out;

  char* ws = (char*)d_ws;
  u16* Abf  = (u16*)(ws + 0);            //  8,388,608 B
  u16* W2   = (u16*)(ws + 8388608);      //     16,384
  u16* W3   = (u16*)(ws + 8404992);      //     49,152
  u16* W4   = (u16*)(ws + 8454144);      //     16,384
  u16* W5   = (u16*)(ws + 8470528);      //     49,152
  u16* bufA = (u16*)(ws + 8519680);      // 92,274,688
  u16* bufB = (u16*)(ws + 100794368);    // 92,274,688
  u16* W1   = (u16*)(ws + 8519680 + 88000000);  // 2 KB, in bufA tail slack
  u16* FWT  = (u16*)(ws + 8519680 + 88004096);  // 28,672 B, bufA tail slack

  prep_all<<<4412, 256, 0, stream>>>(A, Abf, out + 393216,
                                     tb1w, W1, tb2w, W2, tb3w, W3,
                                     tb4w, W4, tb5w, W5, fw, FWT);

  // ---- block 1:  U1 = TB1(x)*th1; t2 = relu(A*U1); U2' = TB3(TB2(t2))*th2
  tb1_kernel<<<dim3(8, 16, 22), 256, 0, stream>>>(x, W1, tb1b, th1, bufA);
  sp_gemm<1><<<44 * 16, 256, 0, stream>>>(Abf, bufA, bufB, 5632);
  tbf_fused<22, 1><<<512, 256, 0, stream>>>(bufB, W2, tb2b, W3, tb3b, th2,
                                            nullptr, nullptr, bufA, nullptr);
  // ---- block 2:  t2 = relu(A*U2); out = FC(TB5(TB4(t2)))
  sp_gemm<1><<<36 * 16, 256, 0, stream>>>(Abf, bufA, bufB, 4608);
  tbf_fused<18, 0><<<512, 256, 0, stream>>>(bufB, W4, tb4b, W5, tb5b, nullptr,
                                            FWT, fb, nullptr, out);
}